// Round 1
// baseline (402.569 us; speedup 1.0000x reference)
//
#include <hip/hip_runtime.h>
#include <math.h>

#define NUM_CL 80
#define A0 4800
#define A1 1200
#define A2 300
#define A_TOTAL 6300
#define B_IMG 64
#define T_TGT 1024
#define TOPK 10

__device__ __forceinline__ void anchor_of(int a, float& ax, float& ay, float& s) {
    if (a < A0) {
        int gx = a % 80, gy = a / 80;
        ax = (gx + 0.5f) * 8.0f; ay = (gy + 0.5f) * 8.0f; s = 8.0f;
    } else if (a < A0 + A1) {
        int al = a - A0;
        int gx = al % 40, gy = al / 40;
        ax = (gx + 0.5f) * 16.0f; ay = (gy + 0.5f) * 16.0f; s = 16.0f;
    } else {
        int al = a - (A0 + A1);
        int gx = al % 20, gy = al / 20;
        ax = (gx + 0.5f) * 32.0f; ay = (gy + 0.5f) * 32.0f; s = 32.0f;
    }
}

__device__ __forceinline__ const float* elem_ptr(const float* o0, const float* o1,
                                                 const float* o2, int b, int a) {
    if (a < A0)      return o0 + ((size_t)b * A0 + a) * 85;
    if (a < A0 + A1) return o1 + ((size_t)b * A1 + (a - A0)) * 85;
    return o2 + ((size_t)b * A2 + (a - A0 - A1)) * 85;
}

__device__ __forceinline__ float bce_logit(float x, float t) {
    return fmaxf(x, 0.0f) - x * t + log1pf(expf(-fabsf(x)));
}

// ---------------- init workspace ----------------
__global__ void init_kernel(int* __restrict__ matched, int* __restrict__ first_t,
                            int* __restrict__ n_fg, float* __restrict__ box_sum,
                            float* __restrict__ cls_sum, float* __restrict__ obj_sum) {
    int i = blockIdx.x * blockDim.x + threadIdx.x;
    if (i < B_IMG * A_TOTAL) matched[i] = -1;
    if (i < B_IMG) {
        first_t[i] = T_TGT;
        n_fg[i] = 0;
        box_sum[i] = 0.0f;
        cls_sum[i] = 0.0f;
    }
    if (i == 0) obj_sum[0] = 0.0f;
}

// ---------------- matching: one wave per target ----------------
__global__ void match_kernel(const float* __restrict__ targets,
                             int* __restrict__ matched, int* __restrict__ first_t) {
    int gtid = blockIdx.x * blockDim.x + threadIdx.x;
    int t = gtid >> 6;          // one 64-lane wave per target
    int lane = threadIdx.x & 63;
    // grid sized exactly: t < T_TGT always

    int img = (int)targets[t * 6 + 0];
    float gcx = targets[t * 6 + 2] * 640.0f;
    float gcy = targets[t * 6 + 3] * 480.0f;
    if (lane == 0) atomicMin(&first_t[img], t);

    // per-lane local top-10 sorted ascending by (dist, index)
    float d[TOPK];
    int id[TOPK];
#pragma unroll
    for (int j = 0; j < TOPK; ++j) { d[j] = INFINITY; id[j] = 0x7FFFFFFF; }

    for (int a = lane; a < A_TOTAL; a += 64) {
        float ax, ay, s;
        anchor_of(a, ax, ay, s);
        float dx = ax - gcx, dy = ay - gcy;
        float dist = sqrtf(dx * dx + dy * dy);
        if (dist < d[TOPK - 1] || (dist == d[TOPK - 1] && a < id[TOPK - 1])) {
            float cd = dist; int ci = a;
#pragma unroll
            for (int j = 0; j < TOPK; ++j) {
                bool sw = (cd < d[j]) || (cd == d[j] && ci < id[j]);
                float od = d[j]; int oi = id[j];
                if (sw) { d[j] = cd; id[j] = ci; cd = od; ci = oi; }
            }
        }
    }

    // spill per-lane lists to LDS as packed keys (dist >= 0 so bit order == value order)
    __shared__ unsigned long long keys[256][TOPK];   // 20 KB
#pragma unroll
    for (int j = 0; j < TOPK; ++j) {
        unsigned int fb = __float_as_uint(d[j]);
        keys[threadIdx.x][j] = ((unsigned long long)fb << 32) | (unsigned int)id[j];
    }
    __syncthreads();

    // extract global top-10 by repeated wave-min
    int head = 0;
    for (int k = 0; k < TOPK; ++k) {
        unsigned long long my =
            (head < TOPK) ? keys[threadIdx.x][head] : 0xFFFFFFFFFFFFFFFFULL;
        unsigned long long m = my;
#pragma unroll
        for (int off = 32; off >= 1; off >>= 1) {
            unsigned long long o = __shfl_xor(m, off, 64);
            m = (o < m) ? o : m;
        }
        if (my == m) head++;   // unique: anchor indices are disjoint across lanes
        if (lane == 0) {
            int aidx = (int)(unsigned int)(m & 0xFFFFFFFFu);
            atomicMax(&matched[img * A_TOTAL + aidx], t);
        }
    }
}

// ---------------- main loss ----------------
__global__ void loss_kernel(const float* __restrict__ o0, const float* __restrict__ o1,
                            const float* __restrict__ o2, const float* __restrict__ targets,
                            const int* __restrict__ matched, const int* __restrict__ first_t,
                            float* __restrict__ obj_sum, float* __restrict__ box_sum,
                            float* __restrict__ cls_sum, int* __restrict__ n_fg) {
    int b = blockIdx.y;
    int a = blockIdx.x * blockDim.x + threadIdx.x;
    float obj_l = 0.0f;
    if (a < A_TOTAL) {
        const float* p = elem_ptr(o0, o1, o2, b, a);
        int m = matched[b * A_TOTAL + a];
        bool fg = (m >= 0);
        float x4 = p[4];
        obj_l = bce_logit(x4, fg ? 1.0f : 0.0f);
        if (fg) {
            float ax, ay, s;
            anchor_of(a, ax, ay, s);
            float x0 = p[0], x1 = p[1], x2 = p[2], x3 = p[3];
            float sig0 = 1.0f / (1.0f + expf(-x0));
            float sig1 = 1.0f / (1.0f + expf(-x1));
            float pcx = (sig0 + ax / s) * s;   // ax/s == gx+0.5 exactly
            float pcy = (sig1 + ay / s) * s;
            float pw = expf(fminf(x2, 4.0f)) * s;
            float ph = expf(fminf(x3, 4.0f)) * s;

            float gcx = targets[m * 6 + 2] * 640.0f;
            float gcy = targets[m * 6 + 3] * 480.0f;
            float gw  = targets[m * 6 + 4] * 640.0f;
            float gh  = targets[m * 6 + 5] * 480.0f;

            const float eps = 1e-7f;
            float px1 = pcx - pw * 0.5f, py1 = pcy - ph * 0.5f;
            float px2 = pcx + pw * 0.5f, py2 = pcy + ph * 0.5f;
            float gx1 = gcx - gw * 0.5f, gy1 = gcy - gh * 0.5f;
            float gx2 = gcx + gw * 0.5f, gy2 = gcy + gh * 0.5f;
            float iw = fmaxf(fminf(px2, gx2) - fmaxf(px1, gx1), 0.0f);
            float ih = fmaxf(fminf(py2, gy2) - fmaxf(py1, gy1), 0.0f);
            float inter = iw * ih;
            float uni = (px2 - px1) * (py2 - py1) + (gx2 - gx1) * (gy2 - gy1) - inter;
            float iou = inter / (uni + eps);
            float dcx = pcx - gcx, dcy = pcy - gcy;
            float cxd = dcx * dcx + dcy * dcy;
            float dmx = fmaxf(px2, gx2) - fminf(px1, gx1);
            float dmy = fmaxf(py2, gy2) - fminf(py1, gy1);
            float diag = dmx * dmx + dmy * dmy + eps;
            float da = atanf(gw / (gh + eps)) - atanf(pw / (ph + eps));
            float v = 0.40528473456935109f * (da * da);   // 4/pi^2
            float alpha = v / (1.0f - iou + v + eps);
            float box_l = 1.0f - iou + cxd / diag + alpha * v;

            int ft = first_t[b];
            if (ft > T_TGT - 1) ft = T_TGT - 1;
            int cls_b = (int)targets[ft * 6 + 1];
            float cl = 0.0f;
#pragma unroll 8
            for (int c = 0; c < NUM_CL; ++c) {
                float x = p[5 + c];
                cl += bce_logit(x, (c == cls_b) ? 1.0f : 0.0f);
            }
            atomicAdd(&box_sum[b], box_l);
            atomicAdd(&cls_sum[b], cl);
            atomicAdd(&n_fg[b], 1);
        }
    }
    // block-reduce obj partial
    __shared__ float red[256];
    red[threadIdx.x] = obj_l;
    __syncthreads();
    for (int sft = 128; sft > 0; sft >>= 1) {
        if (threadIdx.x < sft) red[threadIdx.x] += red[threadIdx.x + sft];
        __syncthreads();
    }
    if (threadIdx.x == 0) atomicAdd(obj_sum, red[0]);
}

// ---------------- finalize ----------------
__global__ void finalize_kernel(const float* __restrict__ obj_sum,
                                const float* __restrict__ box_sum,
                                const float* __restrict__ cls_sum,
                                const int* __restrict__ n_fg, float* __restrict__ out) {
    int b = threadIdx.x;   // 64 threads, one per image
    float nf = (float)n_fg[b];
    float denom = fmaxf(nf, 1.0f);
    float bx = box_sum[b] / denom;
    float cl = cls_sum[b] / (denom * (float)NUM_CL);
    float nt = nf;
#pragma unroll
    for (int off = 32; off >= 1; off >>= 1) {
        bx += __shfl_xor(bx, off, 64);
        cl += __shfl_xor(cl, off, 64);
        nt += __shfl_xor(nt, off, 64);
    }
    if (b == 0) {
        float loss_obj = obj_sum[0] / (float)(B_IMG * A_TOTAL);
        float norm = fmaxf(1.0f, nt / (float)B_IMG);
        out[0] = loss_obj + cl / norm + 5.0f * bx / norm;
    }
}

extern "C" void kernel_launch(void* const* d_in, const int* in_sizes, int n_in,
                              void* d_out, int out_size, void* d_ws, size_t ws_size,
                              hipStream_t stream) {
    const float* o0 = (const float*)d_in[0];
    const float* o1 = (const float*)d_in[1];
    const float* o2 = (const float*)d_in[2];
    const float* tg = (const float*)d_in[3];

    int* matched   = (int*)d_ws;                      // B*A ints
    int* first_t   = matched + B_IMG * A_TOTAL;       // B ints
    int* n_fg      = first_t + B_IMG;                 // B ints
    float* box_sum = (float*)(n_fg + B_IMG);          // B floats
    float* cls_sum = box_sum + B_IMG;                 // B floats
    float* obj_sum = cls_sum + B_IMG;                 // 1 float
    float* out = (float*)d_out;

    int nInit = B_IMG * A_TOTAL;
    init_kernel<<<(nInit + 255) / 256, 256, 0, stream>>>(matched, first_t, n_fg,
                                                         box_sum, cls_sum, obj_sum);
    // 1024 targets * 64 lanes / 256 threads = 256 blocks
    match_kernel<<<(T_TGT * 64) / 256, 256, 0, stream>>>(tg, matched, first_t);
    dim3 grid((A_TOTAL + 255) / 256, B_IMG);
    loss_kernel<<<grid, 256, 0, stream>>>(o0, o1, o2, tg, matched, first_t,
                                          obj_sum, box_sum, cls_sum, n_fg);
    finalize_kernel<<<1, 64, 0, stream>>>(obj_sum, box_sum, cls_sum, n_fg, out);
}

// Round 2
// 292.829 us; speedup vs baseline: 1.3748x; 1.3748x over previous
//
#include <hip/hip_runtime.h>
#include <math.h>

#define NUM_CL 80
#define A0 4800
#define A1 1200
#define A2 300
#define A_TOTAL 6300
#define B_IMG 64
#define T_TGT 1024
#define TOPK 10
#define R0 307200   // B*A0
#define R1 384000   // B*(A0+A1)
#define RT 403200   // B*A_TOTAL
#define MAXFG (T_TGT * TOPK)

__device__ __forceinline__ void anchor_of(int a, float& ax, float& ay, float& s) {
    if (a < A0) {
        int gx = a % 80, gy = a / 80;
        ax = (gx + 0.5f) * 8.0f; ay = (gy + 0.5f) * 8.0f; s = 8.0f;
    } else if (a < A0 + A1) {
        int al = a - A0;
        int gx = al % 40, gy = al / 40;
        ax = (gx + 0.5f) * 16.0f; ay = (gy + 0.5f) * 16.0f; s = 16.0f;
    } else {
        int al = a - (A0 + A1);
        int gx = al % 20, gy = al / 20;
        ax = (gx + 0.5f) * 32.0f; ay = (gy + 0.5f) * 32.0f; s = 32.0f;
    }
}

__device__ __forceinline__ const float* elem_ptr(const float* o0, const float* o1,
                                                 const float* o2, int b, int a) {
    if (a < A0)      return o0 + ((size_t)b * A0 + a) * 85;
    if (a < A0 + A1) return o1 + ((size_t)b * A1 + (a - A0)) * 85;
    return o2 + ((size_t)b * A2 + (a - A0 - A1)) * 85;
}

__device__ __forceinline__ float bce_fast(float x, float t) {
    return fmaxf(x, 0.0f) - x * t + __logf(1.0f + __expf(-fabsf(x)));
}

// ---------------- init workspace ----------------
__global__ void init_kernel(int* __restrict__ matched, int* __restrict__ first_t,
                            int* __restrict__ n_fg, float* __restrict__ box_sum,
                            float* __restrict__ cls_sum, float* __restrict__ obj_acc,
                            int* __restrict__ count) {
    int i = blockIdx.x * blockDim.x + threadIdx.x;
    int4* m4 = (int4*)matched;
    if (i < RT / 4) m4[i] = make_int4(-1, -1, -1, -1);
    if (i < B_IMG) {
        first_t[i] = T_TGT;
        n_fg[i] = 0;
        box_sum[i] = 0.0f;
        cls_sum[i] = 0.0f;
        obj_acc[i] = 0.0f;
    }
    if (i == 0) *count = 0;
}

// ---------------- matching: one THREAD per target, 43 geometric candidates ----
// Top-10 nearest anchors provably lie in: 5x5 window @ stride 8 (10th-nearest
// <= 2.0 cells = 16px; outside window >= 20px), 3x3 @ 16 (outside >= 24px),
// 3x3 @ 32 (outside >= 48px). Lex (dist,index) order == jax top_k tie-break.
__global__ void match_kernel(const float* __restrict__ tg,
                             int* __restrict__ matched, int* __restrict__ first_t) {
    int t = blockIdx.x * blockDim.x + threadIdx.x;
    if (t >= T_TGT) return;
    int img = (int)tg[t * 6 + 0];
    float gcx = tg[t * 6 + 2] * 640.0f;
    float gcy = tg[t * 6 + 3] * 480.0f;
    atomicMin(&first_t[img], t);

    float d[TOPK];
    int id[TOPK];
#pragma unroll
    for (int j = 0; j < TOPK; ++j) { d[j] = INFINITY; id[j] = 0x7FFFFFFF; }

    auto scan_scale = [&](float s, int W, int H, int base, int r) {
        int nx = (int)floorf(gcx / s);
        int ny = (int)floorf(gcy / s);
        for (int dy = -r; dy <= r; ++dy) {
            int iy = ny + dy;
            if (iy < 0 || iy >= H) continue;
            float ay = (iy + 0.5f) * s;
            float ddy = ay - gcy;
            for (int dx = -r; dx <= r; ++dx) {
                int ix = nx + dx;
                if (ix < 0 || ix >= W) continue;
                float ax = (ix + 0.5f) * s;
                float ddx = ax - gcx;
                float dist = sqrtf(ddx * ddx + ddy * ddy);
                int ai = base + iy * W + ix;
                if (dist < d[TOPK - 1] || (dist == d[TOPK - 1] && ai < id[TOPK - 1])) {
                    float cd = dist; int ci = ai;
#pragma unroll
                    for (int j = 0; j < TOPK; ++j) {
                        bool sw = (cd < d[j]) || (cd == d[j] && ci < id[j]);
                        float od = d[j]; int oi = id[j];
                        if (sw) { d[j] = cd; id[j] = ci; cd = od; ci = oi; }
                    }
                }
            }
        }
    };
    scan_scale(8.0f,  80, 60, 0, 2);
    scan_scale(16.0f, 40, 30, A0, 1);
    scan_scale(32.0f, 20, 15, A0 + A1, 1);

#pragma unroll
    for (int k = 0; k < TOPK; ++k)
        atomicMax(&matched[img * A_TOTAL + id[k]], t);
}

// ---------------- dense scan: obj softplus sum + fg compaction ----------------
// bce(x, fg) = softplus(x) + fg*(-x); the -x correction is added in fg_kernel.
__global__ void scan_kernel(const float* __restrict__ o0, const float* __restrict__ o1,
                            const float* __restrict__ o2, const int* __restrict__ matched,
                            unsigned* __restrict__ fgl, int* __restrict__ count,
                            float* __restrict__ obj_acc) {
    int g = blockIdx.x * blockDim.x + threadIdx.x;  // exactly RT threads
    int lane = threadIdx.x & 63;

    float x4;
    int mi;
    if (g < R0) {
        x4 = o0[g * 85 + 4];
        int b = g / A0, a = g - b * A0;
        mi = b * A_TOTAL + a;
    } else if (g < R1) {
        int r = g - R0;
        x4 = o1[r * 85 + 4];
        int b = r / A1, a = A0 + (r - b * A1);
        mi = b * A_TOTAL + a;
    } else {
        int r = g - R1;
        x4 = o2[r * 85 + 4];
        int b = r / A2, a = A0 + A1 + (r - b * A2);
        mi = b * A_TOTAL + a;
    }
    int m = matched[mi];

    float sp = fmaxf(x4, 0.0f) + __logf(1.0f + __expf(-fabsf(x4)));
    float rsum = sp;
#pragma unroll
    for (int off = 32; off >= 1; off >>= 1) rsum += __shfl_xor(rsum, off, 64);
    if (lane == 0) atomicAdd(&obj_acc[blockIdx.x & 63], rsum);

    bool fg = (m >= 0);
    unsigned long long mask = __ballot(fg);
    if (mask) {
        int cnt = __popcll(mask);
        int base = 0;
        if (lane == 0) base = atomicAdd(count, cnt);
        base = __shfl(base, 0, 64);
        if (fg) {
            int off = __popcll(mask & ((1ull << lane) - 1ull));
            fgl[base + off] = (unsigned)mi | ((unsigned)m << 19);
        }
    }
}

// ---------------- sparse fg: one wave per fg anchor ----------------
__global__ void fg_kernel(const float* __restrict__ o0, const float* __restrict__ o1,
                          const float* __restrict__ o2, const float* __restrict__ tg,
                          const unsigned* __restrict__ fgl, const int* __restrict__ count,
                          const int* __restrict__ first_t, float* __restrict__ box_sum,
                          float* __restrict__ cls_sum, float* __restrict__ obj_acc,
                          int* __restrict__ n_fg) {
    int wid = (blockIdx.x * blockDim.x + threadIdx.x) >> 6;
    int lane = threadIdx.x & 63;
    if (wid >= *count) return;

    unsigned e = fgl[wid];
    int mi = e & 0x7FFFF;
    int m = (int)(e >> 19);
    int b = mi / A_TOTAL;
    int a = mi - b * A_TOTAL;
    const float* p = elem_ptr(o0, o1, o2, b, a);

    float v0 = p[lane];                              // channels 0..63
    float v1 = (lane < 21) ? p[64 + lane] : 0.0f;    // channels 64..84

    int ft = first_t[b];
    if (ft > T_TGT - 1) ft = T_TGT - 1;
    int clsb = (int)tg[ft * 6 + 1];

    float cl = 0.0f;
    if (lane >= 5) cl = bce_fast(v0, ((lane - 5) == clsb) ? 1.0f : 0.0f);
    if (lane < 21) cl += bce_fast(v1, ((lane + 59) == clsb) ? 1.0f : 0.0f);
#pragma unroll
    for (int off = 32; off >= 1; off >>= 1) cl += __shfl_xor(cl, off, 64);

    float x0 = __shfl(v0, 0, 64), x1 = __shfl(v0, 1, 64);
    float x2 = __shfl(v0, 2, 64), x3 = __shfl(v0, 3, 64);
    float x4 = __shfl(v0, 4, 64);

    if (lane == 0) {
        float ax, ay, s;
        anchor_of(a, ax, ay, s);
        float sig0 = 1.0f / (1.0f + expf(-x0));
        float sig1 = 1.0f / (1.0f + expf(-x1));
        float pcx = (sig0 + ax / s) * s;
        float pcy = (sig1 + ay / s) * s;
        float pw = expf(fminf(x2, 4.0f)) * s;
        float ph = expf(fminf(x3, 4.0f)) * s;

        float gcx = tg[m * 6 + 2] * 640.0f;
        float gcy = tg[m * 6 + 3] * 480.0f;
        float gw  = tg[m * 6 + 4] * 640.0f;
        float gh  = tg[m * 6 + 5] * 480.0f;

        const float eps = 1e-7f;
        float px1 = pcx - pw * 0.5f, py1 = pcy - ph * 0.5f;
        float px2 = pcx + pw * 0.5f, py2 = pcy + ph * 0.5f;
        float gx1 = gcx - gw * 0.5f, gy1 = gcy - gh * 0.5f;
        float gx2 = gcx + gw * 0.5f, gy2 = gcy + gh * 0.5f;
        float iw = fmaxf(fminf(px2, gx2) - fmaxf(px1, gx1), 0.0f);
        float ih = fmaxf(fminf(py2, gy2) - fmaxf(py1, gy1), 0.0f);
        float inter = iw * ih;
        float uni = (px2 - px1) * (py2 - py1) + (gx2 - gx1) * (gy2 - gy1) - inter;
        float iou = inter / (uni + eps);
        float dcx = pcx - gcx, dcy = pcy - gcy;
        float cxd = dcx * dcx + dcy * dcy;
        float dmx = fmaxf(px2, gx2) - fminf(px1, gx1);
        float dmy = fmaxf(py2, gy2) - fminf(py1, gy1);
        float diag = dmx * dmx + dmy * dmy + eps;
        float da = atanf(gw / (gh + eps)) - atanf(pw / (ph + eps));
        float v = 0.40528473456935109f * (da * da);
        float alpha = v / (1.0f - iou + v + eps);
        float box_l = 1.0f - iou + cxd / diag + alpha * v;

        atomicAdd(&box_sum[b], box_l);
        atomicAdd(&cls_sum[b], cl);
        atomicAdd(&obj_acc[b], -x4);   // bce(x,1)-bce(x,0) = -x
        atomicAdd(&n_fg[b], 1);
    }
}

// ---------------- finalize ----------------
__global__ void finalize_kernel(const float* __restrict__ obj_acc,
                                const float* __restrict__ box_sum,
                                const float* __restrict__ cls_sum,
                                const int* __restrict__ n_fg, float* __restrict__ out) {
    int b = threadIdx.x;   // 64 threads
    float nf = (float)n_fg[b];
    float denom = fmaxf(nf, 1.0f);
    float bx = box_sum[b] / denom;
    float cl = cls_sum[b] / (denom * (float)NUM_CL);
    float ob = obj_acc[b];
    float nt = nf;
#pragma unroll
    for (int off = 32; off >= 1; off >>= 1) {
        bx += __shfl_xor(bx, off, 64);
        cl += __shfl_xor(cl, off, 64);
        ob += __shfl_xor(ob, off, 64);
        nt += __shfl_xor(nt, off, 64);
    }
    if (b == 0) {
        float loss_obj = ob / (float)RT;
        float norm = fmaxf(1.0f, nt / (float)B_IMG);
        out[0] = loss_obj + cl / norm + 5.0f * bx / norm;
    }
}

extern "C" void kernel_launch(void* const* d_in, const int* in_sizes, int n_in,
                              void* d_out, int out_size, void* d_ws, size_t ws_size,
                              hipStream_t stream) {
    const float* o0 = (const float*)d_in[0];
    const float* o1 = (const float*)d_in[1];
    const float* o2 = (const float*)d_in[2];
    const float* tg = (const float*)d_in[3];

    int* matched     = (int*)d_ws;                 // RT ints
    unsigned* fgl    = (unsigned*)(matched + RT);  // MAXFG uints
    int* first_t     = (int*)(fgl + MAXFG);        // B ints
    int* n_fg        = first_t + B_IMG;            // B ints
    float* box_sum   = (float*)(n_fg + B_IMG);     // B floats
    float* cls_sum   = box_sum + B_IMG;            // B floats
    float* obj_acc   = cls_sum + B_IMG;            // B floats
    int* count       = (int*)(obj_acc + B_IMG);    // 1 int
    float* out = (float*)d_out;

    init_kernel<<<(RT / 4 + 255) / 256, 256, 0, stream>>>(matched, first_t, n_fg,
                                                          box_sum, cls_sum, obj_acc, count);
    match_kernel<<<T_TGT / 256, 256, 0, stream>>>(tg, matched, first_t);
    scan_kernel<<<RT / 256, 256, 0, stream>>>(o0, o1, o2, matched, fgl, count, obj_acc);
    fg_kernel<<<MAXFG * 64 / 256, 256, 0, stream>>>(o0, o1, o2, tg, fgl, count, first_t,
                                                    box_sum, cls_sum, obj_acc, n_fg);
    finalize_kernel<<<1, 64, 0, stream>>>(obj_acc, box_sum, cls_sum, n_fg, out);
}

// Round 3
// 201.650 us; speedup vs baseline: 1.9964x; 1.4522x over previous
//
#include <hip/hip_runtime.h>
#include <math.h>

#define NUM_CL 80
#define A0 4800
#define A1 1200
#define A2 300
#define A_TOTAL 6300
#define B_IMG 64
#define T_TGT 1024
#define TOPK 10
#define RT 403200          // B * A_TOTAL
#define NCHUNK 25
#define CHUNK_A 252        // 25 * 252 == 6300 exactly
#define NBLK (B_IMG * NCHUNK)

__device__ __forceinline__ void anchor_of(int a, float& ax, float& ay, float& s) {
    if (a < A0) {
        int gx = a % 80, gy = a / 80;
        ax = (gx + 0.5f) * 8.0f; ay = (gy + 0.5f) * 8.0f; s = 8.0f;
    } else if (a < A0 + A1) {
        int al = a - A0;
        int gx = al % 40, gy = al / 40;
        ax = (gx + 0.5f) * 16.0f; ay = (gy + 0.5f) * 16.0f; s = 16.0f;
    } else {
        int al = a - (A0 + A1);
        int gx = al % 20, gy = al / 20;
        ax = (gx + 0.5f) * 32.0f; ay = (gy + 0.5f) * 32.0f; s = 32.0f;
    }
}

__device__ __forceinline__ const float* elem_ptr(const float* o0, const float* o1,
                                                 const float* o2, int b, int a) {
    if (a < A0)      return o0 + ((size_t)b * A0 + a) * 85;
    if (a < A0 + A1) return o1 + ((size_t)b * A1 + (a - A0)) * 85;
    return o2 + ((size_t)b * A2 + (a - A0 - A1)) * 85;
}

__device__ __forceinline__ float bce_fast(float x, float t) {
    return fmaxf(x, 0.0f) - x * t + __logf(1.0f + __expf(-fabsf(x)));
}

// ---------------- init: matched = -1, first_t = T ----------------
__global__ void init_kernel(int* __restrict__ matched, int* __restrict__ first_t) {
    int i = blockIdx.x * blockDim.x + threadIdx.x;
    int4* m4 = (int4*)matched;
    if (i < RT / 4) m4[i] = make_int4(-1, -1, -1, -1);
    if (i < B_IMG) first_t[i] = T_TGT;
}

// ---------------- matching: one THREAD per target, 43 geometric candidates ----
// Top-10 nearest anchors provably lie in: 5x5 window @ stride 8 (10th-nearest
// <= 2.0 cells = 16px; outside window >= 20px), 3x3 @ 16 (outside >= 24px),
// 3x3 @ 32 (outside >= 48px). Lex (dist,index) order == jax top_k tie-break.
// Verified vs reference: absmax 0.0 in R1/R2.
__global__ void match_kernel(const float* __restrict__ tg,
                             int* __restrict__ matched, int* __restrict__ first_t) {
    int t = blockIdx.x * blockDim.x + threadIdx.x;
    if (t >= T_TGT) return;
    int img = (int)tg[t * 6 + 0];
    float gcx = tg[t * 6 + 2] * 640.0f;
    float gcy = tg[t * 6 + 3] * 480.0f;
    atomicMin(&first_t[img], t);

    float d[TOPK];
    int id[TOPK];
#pragma unroll
    for (int j = 0; j < TOPK; ++j) { d[j] = INFINITY; id[j] = 0x7FFFFFFF; }

    auto scan_scale = [&](float s, int W, int H, int base, int r) {
        int nx = (int)floorf(gcx / s);
        int ny = (int)floorf(gcy / s);
        for (int dy = -r; dy <= r; ++dy) {
            int iy = ny + dy;
            if (iy < 0 || iy >= H) continue;
            float ay = (iy + 0.5f) * s;
            float ddy = ay - gcy;
            for (int dx = -r; dx <= r; ++dx) {
                int ix = nx + dx;
                if (ix < 0 || ix >= W) continue;
                float ax = (ix + 0.5f) * s;
                float ddx = ax - gcx;
                float dist = sqrtf(ddx * ddx + ddy * ddy);
                int ai = base + iy * W + ix;
                if (dist < d[TOPK - 1] || (dist == d[TOPK - 1] && ai < id[TOPK - 1])) {
                    float cd = dist; int ci = ai;
#pragma unroll
                    for (int j = 0; j < TOPK; ++j) {
                        bool sw = (cd < d[j]) || (cd == d[j] && ci < id[j]);
                        float od = d[j]; int oi = id[j];
                        if (sw) { d[j] = cd; id[j] = ci; cd = od; ci = oi; }
                    }
                }
            }
        }
    };
    scan_scale(8.0f,  80, 60, 0, 2);
    scan_scale(16.0f, 40, 30, A0, 1);
    scan_scale(32.0f, 20, 15, A0 + A1, 1);

#pragma unroll
    for (int k = 0; k < TOPK; ++k)
        atomicMax(&matched[img * A_TOTAL + id[k]], t);
}

// ---------------- fused dense obj + sparse fg, per (image, chunk) block ------
// partials[blk] = {obj_partial, box_partial, cls_partial, n_fg}
__global__ __launch_bounds__(256) void main_kernel(
        const float* __restrict__ o0, const float* __restrict__ o1,
        const float* __restrict__ o2, const float* __restrict__ tg,
        const int* __restrict__ matched, const int* __restrict__ first_t,
        float4* __restrict__ partials) {
    int blk = blockIdx.x;
    int b = blk / NCHUNK;
    int chunk = blk - b * NCHUNK;
    int tid = threadIdx.x, lane = tid & 63, wid = tid >> 6;
    int a = chunk * CHUNK_A + tid;     // valid when tid < CHUNK_A

    __shared__ unsigned fglist[CHUNK_A];
    __shared__ int nfg_s;
    __shared__ float wred[4][4];       // [qty][wave]: sp, box, cls, objfix
    if (tid == 0) nfg_s = 0;
    __syncthreads();

    // ---- dense phase: softplus(x4) for every anchor; compact fg to LDS ----
    float sp = 0.0f;
    if (tid < CHUNK_A) {
        const float* p = elem_ptr(o0, o1, o2, b, a);
        float x4 = p[4];
        sp = fmaxf(x4, 0.0f) + __logf(1.0f + __expf(-fabsf(x4)));
        int m = matched[b * A_TOTAL + a];
        if (m >= 0) {
            int idx = atomicAdd(&nfg_s, 1);          // LDS atomic
            fglist[idx] = (unsigned)a | ((unsigned)m << 16);
        }
    }
#pragma unroll
    for (int off = 32; off >= 1; off >>= 1) sp += __shfl_xor(sp, off, 64);
    if (lane == 0) wred[0][wid] = sp;
    __syncthreads();
    int nfg = nfg_s;

    // ---- sparse phase: wave-cooperative per fg anchor ----
    float boxacc = 0.0f, clsacc = 0.0f, objfix = 0.0f;
    if (nfg > 0) {
        int ft = first_t[b];
        if (ft > T_TGT - 1) ft = T_TGT - 1;
        int clsb = (int)tg[ft * 6 + 1];

        for (int i = wid; i < nfg; i += 4) {
            unsigned e = fglist[i];
            int a2 = e & 0xFFFF;
            int m  = (int)(e >> 16);
            const float* p = elem_ptr(o0, o1, o2, b, a2);
            float v0 = p[lane];                              // ch 0..63
            float v1 = (lane < 21) ? p[64 + lane] : 0.0f;    // ch 64..84

            float cl = 0.0f;
            if (lane >= 5) cl = bce_fast(v0, ((lane - 5) == clsb) ? 1.0f : 0.0f);
            if (lane < 21) cl += bce_fast(v1, ((lane + 59) == clsb) ? 1.0f : 0.0f);
#pragma unroll
            for (int off = 32; off >= 1; off >>= 1) cl += __shfl_xor(cl, off, 64);

            float x0 = __shfl(v0, 0, 64), x1 = __shfl(v0, 1, 64);
            float x2 = __shfl(v0, 2, 64), x3 = __shfl(v0, 3, 64);
            float x4 = __shfl(v0, 4, 64);

            // box CIoU: all lanes compute identically (wave-uniform, no divergence)
            float ax, ay, s;
            anchor_of(a2, ax, ay, s);
            float sig0 = 1.0f / (1.0f + expf(-x0));
            float sig1 = 1.0f / (1.0f + expf(-x1));
            float pcx = (sig0 + ax / s) * s;
            float pcy = (sig1 + ay / s) * s;
            float pw = expf(fminf(x2, 4.0f)) * s;
            float ph = expf(fminf(x3, 4.0f)) * s;

            float gcx = tg[m * 6 + 2] * 640.0f;
            float gcy = tg[m * 6 + 3] * 480.0f;
            float gw  = tg[m * 6 + 4] * 640.0f;
            float gh  = tg[m * 6 + 5] * 480.0f;

            const float eps = 1e-7f;
            float px1 = pcx - pw * 0.5f, py1 = pcy - ph * 0.5f;
            float px2 = pcx + pw * 0.5f, py2 = pcy + ph * 0.5f;
            float gx1 = gcx - gw * 0.5f, gy1 = gcy - gh * 0.5f;
            float gx2 = gcx + gw * 0.5f, gy2 = gcy + gh * 0.5f;
            float iw = fmaxf(fminf(px2, gx2) - fmaxf(px1, gx1), 0.0f);
            float ih = fmaxf(fminf(py2, gy2) - fmaxf(py1, gy1), 0.0f);
            float inter = iw * ih;
            float uni = (px2 - px1) * (py2 - py1) + (gx2 - gx1) * (gy2 - gy1) - inter;
            float iou = inter / (uni + eps);
            float dcx = pcx - gcx, dcy = pcy - gcy;
            float cxd = dcx * dcx + dcy * dcy;
            float dmx = fmaxf(px2, gx2) - fminf(px1, gx1);
            float dmy = fmaxf(py2, gy2) - fminf(py1, gy1);
            float diag = dmx * dmx + dmy * dmy + eps;
            float da = atanf(gw / (gh + eps)) - atanf(pw / (ph + eps));
            float v = 0.40528473456935109f * (da * da);
            float alpha = v / (1.0f - iou + v + eps);
            float box_l = 1.0f - iou + cxd / diag + alpha * v;

            boxacc += box_l;
            clsacc += cl;       // cl is wave-uniform after reduce
            objfix += -x4;      // bce(x,1)-bce(x,0) = -x
        }
    }
    if (lane == 0) {
        wred[1][wid] = boxacc;
        wred[2][wid] = clsacc;
        wred[3][wid] = objfix;
    }
    __syncthreads();

    if (tid == 0) {
        float4 r;
        r.x = wred[0][0] + wred[0][1] + wred[0][2] + wred[0][3]
            + wred[3][0] + wred[3][1] + wred[3][2] + wred[3][3];
        r.y = wred[1][0] + wred[1][1] + wred[1][2] + wred[1][3];
        r.z = wred[2][0] + wred[2][1] + wred[2][2] + wred[2][3];
        r.w = (float)nfg;
        partials[blk] = r;
    }
}

// ---------------- finalize: 64 threads, one per image ----------------
__global__ void finalize_kernel(const float4* __restrict__ partials,
                                float* __restrict__ out) {
    int b = threadIdx.x;   // 64 threads
    float ob = 0.0f, bx = 0.0f, cl = 0.0f, nf = 0.0f;
#pragma unroll
    for (int c = 0; c < NCHUNK; ++c) {
        float4 r = partials[b * NCHUNK + c];
        ob += r.x; bx += r.y; cl += r.z; nf += r.w;
    }
    float denom = fmaxf(nf, 1.0f);
    bx /= denom;
    cl /= (denom * (float)NUM_CL);
    float nt = nf;
#pragma unroll
    for (int off = 32; off >= 1; off >>= 1) {
        bx += __shfl_xor(bx, off, 64);
        cl += __shfl_xor(cl, off, 64);
        ob += __shfl_xor(ob, off, 64);
        nt += __shfl_xor(nt, off, 64);
    }
    if (b == 0) {
        float loss_obj = ob / (float)RT;
        float norm = fmaxf(1.0f, nt / (float)B_IMG);
        out[0] = loss_obj + cl / norm + 5.0f * bx / norm;
    }
}

extern "C" void kernel_launch(void* const* d_in, const int* in_sizes, int n_in,
                              void* d_out, int out_size, void* d_ws, size_t ws_size,
                              hipStream_t stream) {
    const float* o0 = (const float*)d_in[0];
    const float* o1 = (const float*)d_in[1];
    const float* o2 = (const float*)d_in[2];
    const float* tg = (const float*)d_in[3];

    int* matched     = (int*)d_ws;                   // RT ints
    int* first_t     = matched + RT;                 // B ints
    float4* partials = (float4*)(first_t + B_IMG);   // NBLK float4 (16B-aligned: offset RT*4+256)
    float* out = (float*)d_out;

    init_kernel<<<(RT / 4 + 255) / 256, 256, 0, stream>>>(matched, first_t);
    match_kernel<<<T_TGT / 64, 64, 0, stream>>>(tg, matched, first_t);
    main_kernel<<<NBLK, 256, 0, stream>>>(o0, o1, o2, tg, matched, first_t, partials);
    finalize_kernel<<<1, 64, 0, stream>>>(partials, out);
}

// Round 4
// 196.193 us; speedup vs baseline: 2.0519x; 1.0278x over previous
//
#include <hip/hip_runtime.h>
#include <math.h>

#define NUM_CL 80
#define A0 4800
#define A1 1200
#define A2 300
#define A_TOTAL 6300
#define B_IMG 64
#define T_TGT 1024
#define TOPK 10
#define RT 403200          // B * A_TOTAL
#define NCHUNK 25
#define CHUNK_A 252        // 25 * 252 == 6300 exactly
#define NBLK (B_IMG * NCHUNK)

__device__ __forceinline__ void anchor_of(int a, float& ax, float& ay, float& s) {
    if (a < A0) {
        int gx = a % 80, gy = a / 80;
        ax = (gx + 0.5f) * 8.0f; ay = (gy + 0.5f) * 8.0f; s = 8.0f;
    } else if (a < A0 + A1) {
        int al = a - A0;
        int gx = al % 40, gy = al / 40;
        ax = (gx + 0.5f) * 16.0f; ay = (gy + 0.5f) * 16.0f; s = 16.0f;
    } else {
        int al = a - (A0 + A1);
        int gx = al % 20, gy = al / 20;
        ax = (gx + 0.5f) * 32.0f; ay = (gy + 0.5f) * 32.0f; s = 32.0f;
    }
}

__device__ __forceinline__ const float* elem_ptr(const float* o0, const float* o1,
                                                 const float* o2, int b, int a) {
    if (a < A0)      return o0 + ((size_t)b * A0 + a) * 85;
    if (a < A0 + A1) return o1 + ((size_t)b * A1 + (a - A0)) * 85;
    return o2 + ((size_t)b * A2 + (a - A0 - A1)) * 85;
}

__device__ __forceinline__ float bce_fast(float x, float t) {
    return fmaxf(x, 0.0f) - x * t + __logf(1.0f + __expf(-fabsf(x)));
}

// ---------------- fully fused: per-block local matching + dense obj + fg ----
// Matching (verified absmax 0.0 in R1-R3): top-10 nearest anchors per target
// provably lie in 5x5 @ stride 8, 3x3 @ 16, 3x3 @ 32 windows; lex (dist,index)
// order reproduces jax top_k tie-breaking. Each block recomputes matching for
// its image's ~16 targets into LDS (no global matched array, no init pass).
// partials[blk] = {obj_partial, box_partial, cls_partial, n_fg}
__global__ __launch_bounds__(256) void main_kernel(
        const float* __restrict__ o0, const float* __restrict__ o1,
        const float* __restrict__ o2, const float* __restrict__ tg,
        float4* __restrict__ partials) {
    int blk = blockIdx.x;
    int b = blk / NCHUNK;
    int chunk = blk - b * NCHUNK;
    int tid = threadIdx.x, lane = tid & 63, wid = tid >> 6;
    int abase = chunk * CHUNK_A;
    int a = abase + tid;               // valid when tid < CHUNK_A

    __shared__ int tlist[T_TGT];       // targets belonging to image b
    __shared__ int ntgt_s, first_t_s, nfg_s;
    __shared__ int matched_s[CHUNK_A];
    __shared__ unsigned fglist[CHUNK_A];
    __shared__ float wred[4][4];       // [qty][wave]: sp, box, cls, objfix

    if (tid == 0) { ntgt_s = 0; first_t_s = T_TGT; nfg_s = 0; }
    if (tid < CHUNK_A) matched_s[tid] = -1;
    __syncthreads();

    // ---- gather this image's targets (img field broadcast-read from L2) ----
    for (int t = tid; t < T_TGT; t += 256) {
        if ((int)tg[t * 6 + 0] == b) {
            int i = atomicAdd(&ntgt_s, 1);
            tlist[i] = t;
            atomicMin(&first_t_s, t);
        }
    }
    __syncthreads();
    int ntgt = ntgt_s;

    // ---- local matching: each thread handles one target ----
    for (int i = tid; i < ntgt; i += 256) {
        int t = tlist[i];
        float gcx = tg[t * 6 + 2] * 640.0f;
        float gcy = tg[t * 6 + 3] * 480.0f;

        float d[TOPK];
        int id[TOPK];
#pragma unroll
        for (int j = 0; j < TOPK; ++j) { d[j] = INFINITY; id[j] = 0x7FFFFFFF; }

        auto scan_scale = [&](float s, int W, int H, int base, int r) {
            int nx = (int)floorf(gcx / s);
            int ny = (int)floorf(gcy / s);
            for (int dy = -r; dy <= r; ++dy) {
                int iy = ny + dy;
                if (iy < 0 || iy >= H) continue;
                float ay = (iy + 0.5f) * s;
                float ddy = ay - gcy;
                for (int dx = -r; dx <= r; ++dx) {
                    int ix = nx + dx;
                    if (ix < 0 || ix >= W) continue;
                    float ax = (ix + 0.5f) * s;
                    float ddx = ax - gcx;
                    float dist = sqrtf(ddx * ddx + ddy * ddy);
                    int ai = base + iy * W + ix;
                    if (dist < d[TOPK - 1] || (dist == d[TOPK - 1] && ai < id[TOPK - 1])) {
                        float cd = dist; int ci = ai;
#pragma unroll
                        for (int j = 0; j < TOPK; ++j) {
                            bool sw = (cd < d[j]) || (cd == d[j] && ci < id[j]);
                            float od = d[j]; int oi = id[j];
                            if (sw) { d[j] = cd; id[j] = ci; cd = od; ci = oi; }
                        }
                    }
                }
            }
        };
        scan_scale(8.0f,  80, 60, 0, 2);
        scan_scale(16.0f, 40, 30, A0, 1);
        scan_scale(32.0f, 20, 15, A0 + A1, 1);

#pragma unroll
        for (int k = 0; k < TOPK; ++k) {
            int rel = id[k] - abase;
            if (rel >= 0 && rel < CHUNK_A) atomicMax(&matched_s[rel], t);
        }
    }
    __syncthreads();

    // ---- dense phase: softplus(x4) for every anchor; compact fg to LDS ----
    float sp = 0.0f;
    if (tid < CHUNK_A) {
        const float* p = elem_ptr(o0, o1, o2, b, a);
        float x4 = p[4];
        sp = fmaxf(x4, 0.0f) + __logf(1.0f + __expf(-fabsf(x4)));
        int m = matched_s[tid];
        if (m >= 0) {
            int idx = atomicAdd(&nfg_s, 1);
            fglist[idx] = (unsigned)a | ((unsigned)m << 16);
        }
    }
#pragma unroll
    for (int off = 32; off >= 1; off >>= 1) sp += __shfl_xor(sp, off, 64);
    if (lane == 0) wred[0][wid] = sp;
    __syncthreads();
    int nfg = nfg_s;

    // ---- sparse phase: wave-cooperative per fg anchor ----
    float boxacc = 0.0f, clsacc = 0.0f, objfix = 0.0f;
    if (nfg > 0) {
        int ft = first_t_s;
        if (ft > T_TGT - 1) ft = T_TGT - 1;
        int clsb = (int)tg[ft * 6 + 1];

        for (int i = wid; i < nfg; i += 4) {
            unsigned e = fglist[i];
            int a2 = e & 0xFFFF;
            int m  = (int)(e >> 16);
            const float* p = elem_ptr(o0, o1, o2, b, a2);
            float v0 = p[lane];                              // ch 0..63
            float v1 = (lane < 21) ? p[64 + lane] : 0.0f;    // ch 64..84

            float cl = 0.0f;
            if (lane >= 5) cl = bce_fast(v0, ((lane - 5) == clsb) ? 1.0f : 0.0f);
            if (lane < 21) cl += bce_fast(v1, ((lane + 59) == clsb) ? 1.0f : 0.0f);
#pragma unroll
            for (int off = 32; off >= 1; off >>= 1) cl += __shfl_xor(cl, off, 64);

            float x0 = __shfl(v0, 0, 64), x1 = __shfl(v0, 1, 64);
            float x2 = __shfl(v0, 2, 64), x3 = __shfl(v0, 3, 64);
            float x4 = __shfl(v0, 4, 64);

            // box CIoU: all lanes compute identically (wave-uniform)
            float ax, ay, s;
            anchor_of(a2, ax, ay, s);
            float sig0 = 1.0f / (1.0f + expf(-x0));
            float sig1 = 1.0f / (1.0f + expf(-x1));
            float pcx = (sig0 + ax / s) * s;
            float pcy = (sig1 + ay / s) * s;
            float pw = expf(fminf(x2, 4.0f)) * s;
            float ph = expf(fminf(x3, 4.0f)) * s;

            float gcx = tg[m * 6 + 2] * 640.0f;
            float gcy = tg[m * 6 + 3] * 480.0f;
            float gw  = tg[m * 6 + 4] * 640.0f;
            float gh  = tg[m * 6 + 5] * 480.0f;

            const float eps = 1e-7f;
            float px1 = pcx - pw * 0.5f, py1 = pcy - ph * 0.5f;
            float px2 = pcx + pw * 0.5f, py2 = pcy + ph * 0.5f;
            float gx1 = gcx - gw * 0.5f, gy1 = gcy - gh * 0.5f;
            float gx2 = gcx + gw * 0.5f, gy2 = gcy + gh * 0.5f;
            float iw = fmaxf(fminf(px2, gx2) - fmaxf(px1, gx1), 0.0f);
            float ih = fmaxf(fminf(py2, gy2) - fmaxf(py1, gy1), 0.0f);
            float inter = iw * ih;
            float uni = (px2 - px1) * (py2 - py1) + (gx2 - gx1) * (gy2 - gy1) - inter;
            float iou = inter / (uni + eps);
            float dcx = pcx - gcx, dcy = pcy - gcy;
            float cxd = dcx * dcx + dcy * dcy;
            float dmx = fmaxf(px2, gx2) - fminf(px1, gx1);
            float dmy = fmaxf(py2, gy2) - fminf(py1, gy1);
            float diag = dmx * dmx + dmy * dmy + eps;
            float da = atanf(gw / (gh + eps)) - atanf(pw / (ph + eps));
            float v = 0.40528473456935109f * (da * da);
            float alpha = v / (1.0f - iou + v + eps);
            float box_l = 1.0f - iou + cxd / diag + alpha * v;

            boxacc += box_l;
            clsacc += cl;
            objfix += -x4;      // bce(x,1)-bce(x,0) = -x
        }
    }
    if (lane == 0) {
        wred[1][wid] = boxacc;
        wred[2][wid] = clsacc;
        wred[3][wid] = objfix;
    }
    __syncthreads();

    if (tid == 0) {
        float4 r;
        r.x = wred[0][0] + wred[0][1] + wred[0][2] + wred[0][3]
            + wred[3][0] + wred[3][1] + wred[3][2] + wred[3][3];
        r.y = wred[1][0] + wred[1][1] + wred[1][2] + wred[1][3];
        r.z = wred[2][0] + wred[2][1] + wred[2][2] + wred[2][3];
        r.w = (float)nfg;
        partials[blk] = r;
    }
}

// ---------------- finalize: 64 threads, one per image ----------------
__global__ void finalize_kernel(const float4* __restrict__ partials,
                                float* __restrict__ out) {
    int b = threadIdx.x;   // 64 threads
    float ob = 0.0f, bx = 0.0f, cl = 0.0f, nf = 0.0f;
#pragma unroll
    for (int c = 0; c < NCHUNK; ++c) {
        float4 r = partials[b * NCHUNK + c];
        ob += r.x; bx += r.y; cl += r.z; nf += r.w;
    }
    float denom = fmaxf(nf, 1.0f);
    bx /= denom;
    cl /= (denom * (float)NUM_CL);
    float nt = nf;
#pragma unroll
    for (int off = 32; off >= 1; off >>= 1) {
        bx += __shfl_xor(bx, off, 64);
        cl += __shfl_xor(cl, off, 64);
        ob += __shfl_xor(ob, off, 64);
        nt += __shfl_xor(nt, off, 64);
    }
    if (b == 0) {
        float loss_obj = ob / (float)RT;
        float norm = fmaxf(1.0f, nt / (float)B_IMG);
        out[0] = loss_obj + cl / norm + 5.0f * bx / norm;
    }
}

extern "C" void kernel_launch(void* const* d_in, const int* in_sizes, int n_in,
                              void* d_out, int out_size, void* d_ws, size_t ws_size,
                              hipStream_t stream) {
    const float* o0 = (const float*)d_in[0];
    const float* o1 = (const float*)d_in[1];
    const float* o2 = (const float*)d_in[2];
    const float* tg = (const float*)d_in[3];

    float4* partials = (float4*)d_ws;   // NBLK float4 = 25.6 KB
    float* out = (float*)d_out;

    main_kernel<<<NBLK, 256, 0, stream>>>(o0, o1, o2, tg, partials);
    finalize_kernel<<<1, 64, 0, stream>>>(partials, out);
}